// Round 5
// baseline (165.269 us; speedup 1.0000x reference)
//
#include <hip/hip_runtime.h>

// Problem dims (hardcoded from reference)
#define T_STEPS 100
#define B_N     128
#define IN_F    512
#define OUT_F   512
#define KPAD    128   // T padded to 128 for MFMA K

// fp64 decay constants: exp(-DT/TAU_*)
#define ALPHA_D 0.8187307530779818   // exp(-1/5)   synaptic
#define BETA_D  0.9512294245007140   // exp(-1/20)  membrane

typedef __attribute__((ext_vector_type(8))) short bf16x8;
typedef __attribute__((ext_vector_type(4))) float f32x4;

static __device__ __forceinline__ unsigned int f2bf(float f) {
    union { float f; unsigned int u; } v; v.f = f;
    return (v.u + 0x7FFFu + ((v.u >> 16) & 1u)) >> 16;   // RNE
}

// ---------------------------------------------------------------------------
// K1: transpose W (OUT x IN) -> Wt (IN x OUT).
// ---------------------------------------------------------------------------
__global__ __launch_bounds__(256) void transposeW(const float* __restrict__ W,
                                                  float* __restrict__ Wt) {
    __shared__ float tile[32][33];
    const int bx = blockIdx.x & 15;   // i-tile
    const int by = blockIdx.x >> 4;   // o-tile
    const int tx = threadIdx.x & 31;
    const int ty = threadIdx.x >> 5;  // 0..7
#pragma unroll
    for (int k = 0; k < 32; k += 8) {
        int o = by * 32 + ty + k;
        tile[ty + k][tx] = W[o * IN_F + bx * 32 + tx];
    }
    __syncthreads();
#pragma unroll
    for (int k = 0; k < 32; k += 8) {
        int i = bx * 32 + ty + k;
        Wt[i * OUT_F + by * 32 + tx] = tile[tx][ty + k];
    }
}

// ---------------------------------------------------------------------------
// K_X: Xbf[b][i][kpad] = bf16(x[t][b][i]), t>=100 -> 0. Binary -> exact.
// Block per (b, i-range of 128). Loads coalesced (lanes vary i); 16B stores
// at 256B lane-stride merge in L2 (16.8 MB total).
// ---------------------------------------------------------------------------
__global__ __launch_bounds__(256) void x_to_bf16(const float* __restrict__ x,
                                                 unsigned short* __restrict__ Xbf) {
    const int b   = blockIdx.x & (B_N - 1);
    const int i0  = (blockIdx.x >> 7) * 128;
    const int tid = threadIdx.x;

#pragma unroll
    for (int r = 0; r < 8; ++r) {
        const int g = tid + r * 256;        // 2048: c(16) x i(128)
        const int i = i0 + (g & 127);
        const int c = g >> 7;               // 16B chunk = 8 t's
        unsigned int h[4];
#pragma unroll
        for (int jj = 0; jj < 4; ++jj) {
            const int t0 = c * 8 + jj * 2, t1 = t0 + 1;
            float v0 = 0.f, v1 = 0.f;
            if (t0 < T_STEPS) v0 = x[(size_t)t0 * (B_N * IN_F) + b * IN_F + i];
            if (t1 < T_STEPS) v1 = x[(size_t)t1 * (B_N * IN_F) + b * IN_F + i];
            h[jj] = f2bf(v0) | (f2bf(v1) << 16);
        }
        *(uint4*)((char*)Xbf + (size_t)(b * IN_F + i) * (KPAD * 2) + c * 16) =
            make_uint4(h[0], h[1], h[2], h[3]);
    }
}

// ---------------------------------------------------------------------------
// K_A: C[t,b,o] = sum over active i of Wt[i][o], fp64. One block per (t,b).
// ---------------------------------------------------------------------------
__global__ __launch_bounds__(256) void syn_current(const float* __restrict__ x,
                                                   const float* __restrict__ Wt,
                                                   double* __restrict__ C) {
    const int tb  = blockIdx.x;          // t*B + b
    const int tid = threadIdx.x;

    __shared__ int s_idx[IN_F];
    __shared__ int s_cnt;

    if (tid < 64) {                      // wave 0 builds ascending active list
        const float* xr = x + (size_t)tb * IN_F;
        int base = 0;
#pragma unroll
        for (int j = 0; j < 8; ++j) {
            const float v = xr[j * 64 + tid];
            const unsigned long long m = __ballot(v > 0.5f);
            if (v > 0.5f) {
                const int pos = base + __popcll(m & ((1ull << tid) - 1ull));
                s_idx[pos] = j * 64 + tid;
            }
            base += __popcll(m);
        }
        if (tid == 0) s_cnt = base;
    }
    __syncthreads();

    const int cnt = s_cnt;
    double c0 = 0.0, c1 = 0.0;
    const float* W0 = Wt + tid;
    const float* W1 = Wt + tid + 256;
    for (int k = 0; k < cnt; ++k) {
        const int i = s_idx[k];          // LDS broadcast (uniform address)
        c0 += (double)W0[(size_t)i * OUT_F];
        c1 += (double)W1[(size_t)i * OUT_F];
    }

    double* Cr = C + (size_t)tb * OUT_F;
    Cr[tid]       = c0;
    Cr[tid + 256] = c1;
}

// ---------------------------------------------------------------------------
// K_B: elementwise LIF scan, one thread per (b,o). fp64 recurrence,
// double-buffered 10-step chunks (static indices only). Additionally emits
// Pbf[b][o][kpad] = bf16(sigma'(U_post) * gamma^(99-t)) when Pq != nullptr
// (U_post is already in registers -> trace operand precompute is ~free).
// ---------------------------------------------------------------------------
#define LIF_STEP(BUF, J, CB)                                                   \
    {                                                                          \
        const int t = (CB) * 10 + (J);                                         \
        I = ALPHA_D * I + BUF[J];                                              \
        U = BETA_D * U + I;                                                    \
        const double Sv = (U >= 1.0) ? 1.0 : 0.0;                              \
        S_out[(size_t)t * N + pos] = (float)Sv;                                \
        Uh[(size_t)(2 * t) * N + pos] = (float)U;                              \
        U -= Sv;                                                               \
        Uh[(size_t)(2 * t + 1) * N + pos] = (float)U;                          \
        if (Pq) {                                                              \
            const float du = fabsf((float)U - 1.0f);                           \
            const float dd = 1.0f + 0.03f * du;                                \
            const float pv = __expf(-0.05f * (float)(T_STEPS - 1 - t)) / (dd * dd); \
            const unsigned int hw = f2bf(pv);                                  \
            if ((J) & 1) Pq[(size_t)pos * 64 + (t >> 1)] = plo | (hw << 16);   \
            else plo = hw;                                                     \
        }                                                                      \
        U -= Sv;                                                               \
    }

__global__ __launch_bounds__(256) void lif_pointwise(const double* __restrict__ C,
                                                     float* __restrict__ S_out,
                                                     float* __restrict__ Uh,
                                                     unsigned int* __restrict__ Pq) {
    const int pos = blockIdx.x * 256 + threadIdx.x;   // b*OUT + o
    const size_t N = (size_t)B_N * OUT_F;

    double I = 0.0, U = 0.0;
    double bufA[10], bufB[10];
    unsigned int plo = 0;

#pragma unroll
    for (int j = 0; j < 10; ++j) bufA[j] = C[(size_t)j * N + pos];

    for (int cb = 0; cb < 10; cb += 2) {
#pragma unroll
        for (int j = 0; j < 10; ++j) bufB[j] = C[((size_t)(cb + 1) * 10 + j) * N + pos];
#pragma unroll
        for (int j = 0; j < 10; ++j) LIF_STEP(bufA, j, cb)
        if (cb + 2 < 10) {
#pragma unroll
            for (int j = 0; j < 10; ++j) bufA[j] = C[((size_t)(cb + 2) * 10 + j) * N + pos];
        }
#pragma unroll
        for (int j = 0; j < 10; ++j) LIF_STEP(bufB, j, cb + 1)
    }

    if (Pq) {   // zero-pad t = 100..127 (slots 50..63)
#pragma unroll
        for (int k = 0; k < 14; ++k) Pq[(size_t)pos * 64 + 50 + k] = 0u;
    }
}

// ---------------------------------------------------------------------------
// K3 (ws path): trace[b] = P^T @ X from PRECOMPUTED bf16 [row][kpad] buffers.
// Staging = 16 x {uint4 load + swizzled ds_write_b128} per thread, zero VALU
// conversion. Per block 64 KB reads; per-XCD working set 16 b x 256 KB = 4 MB
// ~= L2. Same XOR swizzle / MFMA / epilogue as the proven round-4 kernel.
// ---------------------------------------------------------------------------
__global__ __launch_bounds__(256) void trace_mfma_pre(const unsigned short* __restrict__ Pbf,
                                                      const unsigned short* __restrict__ Xbf,
                                                      float* __restrict__ trace) {
    __shared__ unsigned short Pa[128 * 128];   // [o][k] swizzled, 32 KB
    __shared__ unsigned short Xb[128 * 128];   // [i][k] swizzled, 32 KB

    const int idx  = blockIdx.x;
    const int xcd  = idx & 7;
    const int slot = idx >> 3;                 // 0..255
    const int b    = xcd * 16 + (slot >> 4);   // 16 b's per XCD
    const int tile = slot & 15;
    const int ot   = tile >> 2;                // 0..3
    const int it   = tile & 3;                 // 0..3
    const int tid  = threadIdx.x;

    char* const pbase = (char*)Pa;
    char* const xbase = (char*)Xb;
    const char* const Pg = (const char*)Pbf + (size_t)(b * OUT_F + ot * 128) * (KPAD * 2);
    const char* const Xg = (const char*)Xbf + (size_t)(b * IN_F + it * 128) * (KPAD * 2);

#pragma unroll
    for (int r = 0; r < 8; ++r) {
        const int chunk = tid + r * 256;       // 2048 = 128 rows x 16 chunks
        const int row   = chunk >> 4;
        const int c     = chunk & 15;
        const unsigned int loff = (unsigned int)(row * 256) + ((unsigned int)(c * 16) ^ ((unsigned int)(row & 7) << 4));
        const uint4 vp = *(const uint4*)(Pg + (size_t)row * 256 + c * 16);
        const uint4 vx = *(const uint4*)(Xg + (size_t)row * 256 + c * 16);
        *(uint4*)(pbase + loff) = vp;
        *(uint4*)(xbase + loff) = vx;
    }
    __syncthreads();

    // ---- compute: each wave does a 64x64 quadrant ----
    const int w    = tid >> 6;                 // 0..3
    const int l    = tid & 63;
    const int wo   = (w >> 1) * 64;            // o-quadrant base
    const int wi   = (w & 1) * 64;             // i-quadrant base
    const int lo16 = l & 15;
    const int g4   = l >> 4;                   // 0..3

    f32x4 acc[4][4];
#pragma unroll
    for (int m = 0; m < 4; ++m)
#pragma unroll
        for (int n = 0; n < 4; ++n) acc[m][n] = (f32x4){0.f, 0.f, 0.f, 0.f};

#pragma unroll
    for (int kk = 0; kk < 4; ++kk) {           // K = 4 x 32
        bf16x8 af[4], bfr[4];
#pragma unroll
        for (int m = 0; m < 4; ++m) {
            const int row = wo + m * 16 + lo16;
            const unsigned int off = (unsigned int)(row * 256 + kk * 64 + g4 * 16)
                                     ^ ((unsigned int)(row & 7) << 4);
            af[m] = *(const bf16x8*)(pbase + off);
        }
#pragma unroll
        for (int n = 0; n < 4; ++n) {
            const int row = wi + n * 16 + lo16;
            const unsigned int off = (unsigned int)(row * 256 + kk * 64 + g4 * 16)
                                     ^ ((unsigned int)(row & 7) << 4);
            bfr[n] = *(const bf16x8*)(xbase + off);
        }
#pragma unroll
        for (int m = 0; m < 4; ++m)
#pragma unroll
            for (int n = 0; n < 4; ++n)
                acc[m][n] = __builtin_amdgcn_mfma_f32_16x16x32_bf16(af[m], bfr[n], acc[m][n], 0, 0, 0);
    }

    // ---- epilogue: D col = lane&15, row = (lane>>4)*4 + reg ----
    float* tb = trace + (size_t)b * (OUT_F * IN_F);
#pragma unroll
    for (int m = 0; m < 4; ++m) {
#pragma unroll
        for (int rr = 0; rr < 4; ++rr) {
            const int o = ot * 128 + wo + m * 16 + g4 * 4 + rr;
#pragma unroll
            for (int n = 0; n < 4; ++n) {
                const int i = it * 128 + wi + n * 16 + lo16;
                tb[(size_t)o * IN_F + i] = acc[m][n][rr];
            }
        }
    }
}

// ---------------------------------------------------------------------------
// K3 (fallback, ws too small): round-4 kernel — inline f32 staging+convert.
// ---------------------------------------------------------------------------
__global__ __launch_bounds__(256) void trace_mfma(const float* __restrict__ x,
                                                  const float* __restrict__ Uh,
                                                  float* __restrict__ trace) {
    __shared__ unsigned short Pa[128 * 128];
    __shared__ unsigned short Xb[128 * 128];

    const int idx  = blockIdx.x;
    const int xcd  = idx & 7;
    const int slot = idx >> 3;
    const int b    = xcd * 16 + (slot >> 4);
    const int tile = slot & 15;
    const int ot   = tile >> 2;
    const int it   = tile & 3;
    const int tid  = threadIdx.x;

    char* const pbase = (char*)Pa;
    char* const xbase = (char*)Xb;

#pragma unroll
    for (int r = 0; r < 8; ++r) {
        const int g  = tid + r * 256;
        const int i  = g & 127;
        const int kg = g >> 7;
        unsigned int h[4];
#pragma unroll
        for (int jj = 0; jj < 4; ++jj) {
            const int t0 = kg * 8 + jj * 2, t1 = t0 + 1;
            float v0 = 0.f, v1 = 0.f;
            if (t0 < T_STEPS) v0 = x[(size_t)t0 * (B_N * IN_F) + b * IN_F + it * 128 + i];
            if (t1 < T_STEPS) v1 = x[(size_t)t1 * (B_N * IN_F) + b * IN_F + it * 128 + i];
            h[jj] = f2bf(v0) | (f2bf(v1) << 16);
        }
        unsigned int off = (unsigned int)(i * 256 + kg * 16) ^ ((unsigned int)(i & 7) << 4);
        *(uint4*)(xbase + off) = make_uint4(h[0], h[1], h[2], h[3]);
    }

#pragma unroll
    for (int r = 0; r < 8; ++r) {
        const int g  = tid + r * 256;
        const int o  = g & 127;
        const int kg = g >> 7;
        unsigned int h[4];
#pragma unroll
        for (int jj = 0; jj < 4; ++jj) {
            unsigned int hw[2];
#pragma unroll
            for (int e = 0; e < 2; ++e) {
                const int t = kg * 8 + jj * 2 + e;
                float p = 0.f;
                if (t < T_STEPS) {
                    const float u  = Uh[(size_t)(2 * t + 1) * (B_N * OUT_F) + b * OUT_F + ot * 128 + o];
                    const float du = fabsf(u - 1.0f);
                    const float d  = 1.0f + 0.03f * du;
                    const float gp = __expf(-0.05f * (float)(T_STEPS - 1 - t));
                    p = gp / (d * d);
                }
                hw[e] = f2bf(p);
            }
            h[jj] = hw[0] | (hw[1] << 16);
        }
        unsigned int off = (unsigned int)(o * 256 + kg * 16) ^ ((unsigned int)(o & 7) << 4);
        *(uint4*)(pbase + off) = make_uint4(h[0], h[1], h[2], h[3]);
    }
    __syncthreads();

    const int w    = tid >> 6;
    const int l    = tid & 63;
    const int wo   = (w >> 1) * 64;
    const int wi   = (w & 1) * 64;
    const int lo16 = l & 15;
    const int g4   = l >> 4;

    f32x4 acc[4][4];
#pragma unroll
    for (int m = 0; m < 4; ++m)
#pragma unroll
        for (int n = 0; n < 4; ++n) acc[m][n] = (f32x4){0.f, 0.f, 0.f, 0.f};

#pragma unroll
    for (int kk = 0; kk < 4; ++kk) {
        bf16x8 af[4], bfr[4];
#pragma unroll
        for (int m = 0; m < 4; ++m) {
            const int row = wo + m * 16 + lo16;
            const unsigned int off = (unsigned int)(row * 256 + kk * 64 + g4 * 16)
                                     ^ ((unsigned int)(row & 7) << 4);
            af[m] = *(const bf16x8*)(pbase + off);
        }
#pragma unroll
        for (int n = 0; n < 4; ++n) {
            const int row = wi + n * 16 + lo16;
            const unsigned int off = (unsigned int)(row * 256 + kk * 64 + g4 * 16)
                                     ^ ((unsigned int)(row & 7) << 4);
            bfr[n] = *(const bf16x8*)(xbase + off);
        }
#pragma unroll
        for (int m = 0; m < 4; ++m)
#pragma unroll
            for (int n = 0; n < 4; ++n)
                acc[m][n] = __builtin_amdgcn_mfma_f32_16x16x32_bf16(af[m], bfr[n], acc[m][n], 0, 0, 0);
    }

    float* tb = trace + (size_t)b * (OUT_F * IN_F);
#pragma unroll
    for (int m = 0; m < 4; ++m) {
#pragma unroll
        for (int rr = 0; rr < 4; ++rr) {
            const int o = ot * 128 + wo + m * 16 + g4 * 4 + rr;
#pragma unroll
            for (int n = 0; n < 4; ++n) {
                const int i = it * 128 + wi + n * 16 + lo16;
                tb[(size_t)o * IN_F + i] = acc[m][n][rr];
            }
        }
    }
}

// ---------------------------------------------------------------------------
extern "C" void kernel_launch(void* const* d_in, const int* in_sizes, int n_in,
                              void* d_out, int out_size, void* d_ws, size_t ws_size,
                              hipStream_t stream) {
    const float* x = (const float*)d_in[0];   // (T, B, IN) binary spikes
    const float* W = (const float*)d_in[1];   // (OUT, IN)

    float* out   = (float*)d_out;
    float* S_out = out;                                            // (T, B, OUT)
    float* Uh    = out + (size_t)T_STEPS * B_N * OUT_F;            // (2T, B, OUT)
    float* trace = Uh + (size_t)2 * T_STEPS * B_N * OUT_F;         // (B, OUT, IN)

    // ws layout: Wt (1 MB) | Xbf (16.78 MB) | Pbf (16.78 MB)
    const size_t WT_BYTES = (size_t)IN_F * OUT_F * 4;
    const size_t BF_BYTES = (size_t)B_N * 512 * KPAD * 2;          // 16,777,216
    const bool   ws_ok    = ws_size >= WT_BYTES + 2 * BF_BYTES;

    float*          Wt  = (float*)d_ws;
    unsigned short* Xbf = (unsigned short*)((char*)d_ws + WT_BYTES);
    unsigned short* Pbf = (unsigned short*)((char*)d_ws + WT_BYTES + BF_BYTES);

    // C scratch: reuse the trace region of d_out (134 MB >= 52 MB needed);
    // the trace kernel runs last and overwrites it.
    double* C = (double*)trace;

    transposeW<<<256, 256, 0, stream>>>(W, Wt);
    if (ws_ok) x_to_bf16<<<512, 256, 0, stream>>>(x, Xbf);
    syn_current<<<T_STEPS * B_N, 256, 0, stream>>>(x, Wt, C);
    lif_pointwise<<<B_N * OUT_F / 256, 256, 0, stream>>>(C, S_out, Uh,
                                                         ws_ok ? (unsigned int*)Pbf : nullptr);
    if (ws_ok)
        trace_mfma_pre<<<16 * B_N, 256, 0, stream>>>(Pbf, Xbf, trace);
    else
        trace_mfma<<<16 * B_N, 256, 0, stream>>>(x, Uh, trace);
}

// Round 7
// 160.414 us; speedup vs baseline: 1.0303x; 1.0303x over previous
//
#include <hip/hip_runtime.h>

// Problem dims (hardcoded from reference)
#define T_STEPS 100
#define B_N     128
#define IN_F    512
#define OUT_F   512
#define KPAD    128   // T padded to 128 for MFMA K

// fp64 decay constants: exp(-DT/TAU_*)
#define ALPHA_D 0.8187307530779818   // exp(-1/5)   synaptic
#define BETA_D  0.9512294245007140   // exp(-1/20)  membrane

typedef __attribute__((ext_vector_type(8))) short bf16x8;
typedef __attribute__((ext_vector_type(4))) float f32x4;

static __device__ __forceinline__ unsigned int f2bf(float f) {
    union { float f; unsigned int u; } v; v.f = f;
    return (v.u + 0x7FFFu + ((v.u >> 16) & 1u)) >> 16;   // RNE
}

// ---------------------------------------------------------------------------
// K1: transpose W (OUT x IN) -> Wt (IN x OUT).
// ---------------------------------------------------------------------------
__global__ __launch_bounds__(256) void transposeW(const float* __restrict__ W,
                                                  float* __restrict__ Wt) {
    __shared__ float tile[32][33];
    const int bx = blockIdx.x & 15;   // i-tile
    const int by = blockIdx.x >> 4;   // o-tile
    const int tx = threadIdx.x & 31;
    const int ty = threadIdx.x >> 5;  // 0..7
#pragma unroll
    for (int k = 0; k < 32; k += 8) {
        int o = by * 32 + ty + k;
        tile[ty + k][tx] = W[o * IN_F + bx * 32 + tx];
    }
    __syncthreads();
#pragma unroll
    for (int k = 0; k < 32; k += 8) {
        int i = bx * 32 + ty + k;
        Wt[i * OUT_F + by * 32 + tx] = tile[tx][ty + k];
    }
}

// ---------------------------------------------------------------------------
// K_A: fused grid. Blocks [0, nconv): x -> Xbf bf16 [b][i][kpad] conversion
// (independent work, rides along with syn for free — syn is L2-BW-bound,
// conversion is HBM-bound). Blocks [nconv, nconv+12800): synaptic current
// C[t,b,o] = sum over active i of Wt[i][o] in fp64 (ballot-compacted active
// list, uniform gather loop over L2-resident Wt).
// ---------------------------------------------------------------------------
__global__ __launch_bounds__(256) void syn_plus(const float* __restrict__ x,
                                                const float* __restrict__ Wt,
                                                double* __restrict__ C,
                                                unsigned short* __restrict__ Xbf,
                                                int nconv) {
    const int tid = threadIdx.x;

    if ((int)blockIdx.x < nconv) {
        // ---- x_to_bf16: block cb covers (b, i-range of 128) ----
        const int cb = blockIdx.x;
        const int b  = cb & (B_N - 1);
        const int i0 = (cb >> 7) * 128;
#pragma unroll
        for (int r = 0; r < 8; ++r) {
            const int g = tid + r * 256;        // 2048: c(16) x i(128)
            const int i = i0 + (g & 127);
            const int c = g >> 7;               // 16B chunk = 8 t's
            unsigned int h[4];
#pragma unroll
            for (int jj = 0; jj < 4; ++jj) {
                const int t0 = c * 8 + jj * 2, t1 = t0 + 1;
                float v0 = 0.f, v1 = 0.f;
                if (t0 < T_STEPS) v0 = x[(size_t)t0 * (B_N * IN_F) + b * IN_F + i];
                if (t1 < T_STEPS) v1 = x[(size_t)t1 * (B_N * IN_F) + b * IN_F + i];
                h[jj] = f2bf(v0) | (f2bf(v1) << 16);
            }
            *(uint4*)((char*)Xbf + (size_t)(b * IN_F + i) * (KPAD * 2) + c * 16) =
                make_uint4(h[0], h[1], h[2], h[3]);
        }
        return;
    }

    // ---- syn_current ----
    const int tb = (int)blockIdx.x - nconv;     // t*B + b

    __shared__ int s_idx[IN_F];
    __shared__ int s_cnt;

    if (tid < 64) {                      // wave 0 builds ascending active list
        const float* xr = x + (size_t)tb * IN_F;
        int base = 0;
#pragma unroll
        for (int j = 0; j < 8; ++j) {
            const float v = xr[j * 64 + tid];
            const unsigned long long m = __ballot(v > 0.5f);
            if (v > 0.5f) {
                const int pos = base + __popcll(m & ((1ull << tid) - 1ull));
                s_idx[pos] = j * 64 + tid;
            }
            base += __popcll(m);
        }
        if (tid == 0) s_cnt = base;
    }
    __syncthreads();

    const int cnt = s_cnt;
    double c0 = 0.0, c1 = 0.0;
    const float* W0 = Wt + tid;
    const float* W1 = Wt + tid + 256;
    for (int k = 0; k < cnt; ++k) {
        const int i = s_idx[k];          // LDS broadcast (uniform address)
        c0 += (double)W0[(size_t)i * OUT_F];
        c1 += (double)W1[(size_t)i * OUT_F];
    }

    double* Cr = C + (size_t)tb * OUT_F;
    Cr[tid]       = c0;
    Cr[tid + 256] = c1;
}

// ---------------------------------------------------------------------------
// K_B: elementwise LIF scan, one thread per (b,o). fp64 recurrence,
// double-buffered 10-step chunks (static indices only). Emits
// Pbf[b][o][kpad] = bf16(sigma'(U_post) * gamma^(99-t)) when Pq != nullptr.
// ---------------------------------------------------------------------------
#define LIF_STEP(BUF, J, CB)                                                   \
    {                                                                          \
        const int t = (CB) * 10 + (J);                                         \
        I = ALPHA_D * I + BUF[J];                                              \
        U = BETA_D * U + I;                                                    \
        const double Sv = (U >= 1.0) ? 1.0 : 0.0;                              \
        S_out[(size_t)t * N + pos] = (float)Sv;                                \
        Uh[(size_t)(2 * t) * N + pos] = (float)U;                              \
        U -= Sv;                                                               \
        Uh[(size_t)(2 * t + 1) * N + pos] = (float)U;                          \
        if (Pq) {                                                              \
            const float du = fabsf((float)U - 1.0f);                           \
            const float dd = 1.0f + 0.03f * du;                                \
            const float pv = __expf(-0.05f * (float)(T_STEPS - 1 - t)) / (dd * dd); \
            const unsigned int hw = f2bf(pv);                                  \
            if ((J) & 1) Pq[(size_t)pos * 64 + (t >> 1)] = plo | (hw << 16);   \
            else plo = hw;                                                     \
        }                                                                      \
        U -= Sv;                                                               \
    }

__global__ __launch_bounds__(256) void lif_pointwise(const double* __restrict__ C,
                                                     float* __restrict__ S_out,
                                                     float* __restrict__ Uh,
                                                     unsigned int* __restrict__ Pq) {
    const int pos = blockIdx.x * 256 + threadIdx.x;   // b*OUT + o
    const size_t N = (size_t)B_N * OUT_F;

    double I = 0.0, U = 0.0;
    double bufA[10], bufB[10];
    unsigned int plo = 0;

#pragma unroll
    for (int j = 0; j < 10; ++j) bufA[j] = C[(size_t)j * N + pos];

    for (int cb = 0; cb < 10; cb += 2) {
#pragma unroll
        for (int j = 0; j < 10; ++j) bufB[j] = C[((size_t)(cb + 1) * 10 + j) * N + pos];
#pragma unroll
        for (int j = 0; j < 10; ++j) LIF_STEP(bufA, j, cb)
        if (cb + 2 < 10) {
#pragma unroll
            for (int j = 0; j < 10; ++j) bufA[j] = C[((size_t)(cb + 2) * 10 + j) * N + pos];
        }
#pragma unroll
        for (int j = 0; j < 10; ++j) LIF_STEP(bufB, j, cb + 1)
    }

    if (Pq) {   // zero-pad t = 100..127 (slots 50..63)
#pragma unroll
        for (int k = 0; k < 14; ++k) Pq[(size_t)pos * 64 + 50 + k] = 0u;
    }
}

// ---------------------------------------------------------------------------
// K3: trace[b] = P^T @ X, 128(o) x 64(i) tile per block, 4096 blocks.
// LDS 48 KB -> 3 blocks/CU (was 64 KB -> 2); finer phase interleave.
// Epilogue: acc -> LDS (stride-68 pad) -> coalesced f32x4 NONTEMPORAL
// stores (64 scalar stores -> 8 vec4; nt keeps Pbf/Xbf L2-resident).
// XCD grouping: 16 b's per XCD (4 MB working set = L2).
// ---------------------------------------------------------------------------
__global__ __launch_bounds__(256) void trace_mfma2(const unsigned short* __restrict__ Pbf,
                                                   const unsigned short* __restrict__ Xbf,
                                                   float* __restrict__ trace) {
    __shared__ char smem[49152];
    char* const pbase = smem;            // [128][128] bf16 swz, 32 KB
    char* const xbase = smem + 32768;    // [64][128] bf16 swz, 16 KB

    const int idx  = blockIdx.x;
    const int xcd  = idx & 7;
    const int slot = idx >> 3;                 // 0..511
    const int b    = xcd * 16 + (slot >> 5);   // 16 b's per XCD
    const int tile = slot & 31;
    const int ot   = tile >> 3;                // 0..3 (128-o panel)
    const int it   = tile & 7;                 // 0..7 (64-i panel)
    const int tid  = threadIdx.x;

    const char* const Pg = (const char*)Pbf + (size_t)(b * OUT_F + ot * 128) * (KPAD * 2);
    const char* const Xg = (const char*)Xbf + (size_t)(b * IN_F + it * 64) * (KPAD * 2);

    // ---- stage P: 128 rows x 256 B ----
#pragma unroll
    for (int r = 0; r < 8; ++r) {
        const int chunk = tid + r * 256;       // 2048 = 128 rows x 16 chunks
        const int row   = chunk >> 4;
        const int c     = chunk & 15;
        const unsigned int loff = (unsigned int)(row * 256) +
            ((unsigned int)(c * 16) ^ ((unsigned int)(row & 7) << 4));
        *(uint4*)(pbase + loff) = *(const uint4*)(Pg + (size_t)row * 256 + c * 16);
    }
    // ---- stage X: 64 rows x 256 B ----
#pragma unroll
    for (int r = 0; r < 4; ++r) {
        const int chunk = tid + r * 256;       // 1024 = 64 rows x 16 chunks
        const int row   = chunk >> 4;
        const int c     = chunk & 15;
        const unsigned int loff = (unsigned int)(row * 256) +
            ((unsigned int)(c * 16) ^ ((unsigned int)(row & 7) << 4));
        *(uint4*)(xbase + loff) = *(const uint4*)(Xg + (size_t)row * 256 + c * 16);
    }
    __syncthreads();

    // ---- compute: wave w covers o rows [w*32, w*32+32), all 64 i ----
    const int w    = tid >> 6;                 // 0..3
    const int l    = tid & 63;
    const int lo16 = l & 15;
    const int g4   = l >> 4;                   // 0..3

    f32x4 acc[2][4];
#pragma unroll
    for (int m = 0; m < 2; ++m)
#pragma unroll
        for (int n = 0; n < 4; ++n) acc[m][n] = (f32x4){0.f, 0.f, 0.f, 0.f};

#pragma unroll
    for (int kk = 0; kk < 4; ++kk) {           // K = 4 x 32
        bf16x8 af[2], bfr[4];
#pragma unroll
        for (int m = 0; m < 2; ++m) {
            const int row = w * 32 + m * 16 + lo16;
            const unsigned int off = (unsigned int)(row * 256 + kk * 64 + g4 * 16)
                                     ^ ((unsigned int)(row & 7) << 4);
            af[m] = *(const bf16x8*)(pbase + off);
        }
#pragma unroll
        for (int n = 0; n < 4; ++n) {
            const int row = n * 16 + lo16;
            const unsigned int off = (unsigned int)(row * 256 + kk * 64 + g4 * 16)
                                     ^ ((unsigned int)(row & 7) << 4);
            bfr[n] = *(const bf16x8*)(xbase + off);
        }
#pragma unroll
        for (int m = 0; m < 2; ++m)
#pragma unroll
            for (int n = 0; n < 4; ++n)
                acc[m][n] = __builtin_amdgcn_mfma_f32_16x16x32_bf16(af[m], bfr[n], acc[m][n], 0, 0, 0);
    }

    // ---- epilogue: bounce through LDS for coalesced f32x4 nt stores ----
    __syncthreads();                            // all ds_reads done; smem reusable
    float* const obuf = (float*)smem;           // [128][68] f32 (stride-68 pad), 34 KB
#pragma unroll
    for (int m = 0; m < 2; ++m)
#pragma unroll
        for (int n = 0; n < 4; ++n)
#pragma unroll
            for (int rr = 0; rr < 4; ++rr)
                obuf[(w * 32 + m * 16 + g4 * 4 + rr) * 68 + n * 16 + lo16] = acc[m][n][rr];
    __syncthreads();

    float* const tb = trace + (size_t)b * (OUT_F * IN_F) + (size_t)(ot * 128) * IN_F + it * 64;
#pragma unroll
    for (int p = 0; p < 8; ++p) {
        const int row  = p * 16 + (tid >> 4);   // 0..127
        const int col4 = (tid & 15) * 4;        // 0..60
        const f32x4 v = *(const f32x4*)&obuf[row * 68 + col4];
        __builtin_nontemporal_store(v, (f32x4*)(tb + (size_t)row * IN_F + col4));
    }
}

// ---------------------------------------------------------------------------
// K3 (fallback, ws too small): round-4 kernel — inline f32 staging+convert.
// ---------------------------------------------------------------------------
__global__ __launch_bounds__(256) void trace_mfma(const float* __restrict__ x,
                                                  const float* __restrict__ Uh,
                                                  float* __restrict__ trace) {
    __shared__ unsigned short Pa[128 * 128];
    __shared__ unsigned short Xb[128 * 128];

    const int idx  = blockIdx.x;
    const int xcd  = idx & 7;
    const int slot = idx >> 3;
    const int b    = xcd * 16 + (slot >> 4);
    const int tile = slot & 15;
    const int ot   = tile >> 2;
    const int it   = tile & 3;
    const int tid  = threadIdx.x;

    char* const pbase = (char*)Pa;
    char* const xbase = (char*)Xb;

#pragma unroll
    for (int r = 0; r < 8; ++r) {
        const int g  = tid + r * 256;
        const int i  = g & 127;
        const int kg = g >> 7;
        unsigned int h[4];
#pragma unroll
        for (int jj = 0; jj < 4; ++jj) {
            const int t0 = kg * 8 + jj * 2, t1 = t0 + 1;
            float v0 = 0.f, v1 = 0.f;
            if (t0 < T_STEPS) v0 = x[(size_t)t0 * (B_N * IN_F) + b * IN_F + it * 128 + i];
            if (t1 < T_STEPS) v1 = x[(size_t)t1 * (B_N * IN_F) + b * IN_F + it * 128 + i];
            h[jj] = f2bf(v0) | (f2bf(v1) << 16);
        }
        unsigned int off = (unsigned int)(i * 256 + kg * 16) ^ ((unsigned int)(i & 7) << 4);
        *(uint4*)(xbase + off) = make_uint4(h[0], h[1], h[2], h[3]);
    }

#pragma unroll
    for (int r = 0; r < 8; ++r) {
        const int g  = tid + r * 256;
        const int o  = g & 127;
        const int kg = g >> 7;
        unsigned int h[4];
#pragma unroll
        for (int jj = 0; jj < 4; ++jj) {
            unsigned int hw[2];
#pragma unroll
            for (int e = 0; e < 2; ++e) {
                const int t = kg * 8 + jj * 2 + e;
                float p = 0.f;
                if (t < T_STEPS) {
                    const float u  = Uh[(size_t)(2 * t + 1) * (B_N * OUT_F) + b * OUT_F + ot * 128 + o];
                    const float du = fabsf(u - 1.0f);
                    const float d  = 1.0f + 0.03f * du;
                    const float gp = __expf(-0.05f * (float)(T_STEPS - 1 - t));
                    p = gp / (d * d);
                }
                hw[e] = f2bf(p);
            }
            h[jj] = hw[0] | (hw[1] << 16);
        }
        unsigned int off = (unsigned int)(o * 256 + kg * 16) ^ ((unsigned int)(o & 7) << 4);
        *(uint4*)(pbase + off) = make_uint4(h[0], h[1], h[2], h[3]);
    }
    __syncthreads();

    const int w    = tid >> 6;
    const int l    = tid & 63;
    const int wo   = (w >> 1) * 64;
    const int wi   = (w & 1) * 64;
    const int lo16 = l & 15;
    const int g4   = l >> 4;

    f32x4 acc[4][4];
#pragma unroll
    for (int m = 0; m < 4; ++m)
#pragma unroll
        for (int n = 0; n < 4; ++n) acc[m][n] = (f32x4){0.f, 0.f, 0.f, 0.f};

#pragma unroll
    for (int kk = 0; kk < 4; ++kk) {
        bf16x8 af[4], bfr[4];
#pragma unroll
        for (int m = 0; m < 4; ++m) {
            const int row = wo + m * 16 + lo16;
            const unsigned int off = (unsigned int)(row * 256 + kk * 64 + g4 * 16)
                                     ^ ((unsigned int)(row & 7) << 4);
            af[m] = *(const bf16x8*)(pbase + off);
        }
#pragma unroll
        for (int n = 0; n < 4; ++n) {
            const int row = wi + n * 16 + lo16;
            const unsigned int off = (unsigned int)(row * 256 + kk * 64 + g4 * 16)
                                     ^ ((unsigned int)(row & 7) << 4);
            bfr[n] = *(const bf16x8*)(xbase + off);
        }
#pragma unroll
        for (int m = 0; m < 4; ++m)
#pragma unroll
            for (int n = 0; n < 4; ++n)
                acc[m][n] = __builtin_amdgcn_mfma_f32_16x16x32_bf16(af[m], bfr[n], acc[m][n], 0, 0, 0);
    }

    float* tb = trace + (size_t)b * (OUT_F * IN_F);
#pragma unroll
    for (int m = 0; m < 4; ++m) {
#pragma unroll
        for (int rr = 0; rr < 4; ++rr) {
            const int o = ot * 128 + wo + m * 16 + g4 * 4 + rr;
#pragma unroll
            for (int n = 0; n < 4; ++n) {
                const int i = it * 128 + wi + n * 16 + lo16;
                tb[(size_t)o * IN_F + i] = acc[m][n][rr];
            }
        }
    }
}

// ---------------------------------------------------------------------------
extern "C" void kernel_launch(void* const* d_in, const int* in_sizes, int n_in,
                              void* d_out, int out_size, void* d_ws, size_t ws_size,
                              hipStream_t stream) {
    const float* x = (const float*)d_in[0];   // (T, B, IN) binary spikes
    const float* W = (const float*)d_in[1];   // (OUT, IN)

    float* out   = (float*)d_out;
    float* S_out = out;                                            // (T, B, OUT)
    float* Uh    = out + (size_t)T_STEPS * B_N * OUT_F;            // (2T, B, OUT)
    float* trace = Uh + (size_t)2 * T_STEPS * B_N * OUT_F;         // (B, OUT, IN)

    // ws layout: Wt (1 MB) | Xbf (16.78 MB) | Pbf (16.78 MB)
    const size_t WT_BYTES = (size_t)IN_F * OUT_F * 4;
    const size_t BF_BYTES = (size_t)B_N * 512 * KPAD * 2;          // 16,777,216
    const bool   ws_ok    = ws_size >= WT_BYTES + 2 * BF_BYTES;

    float*          Wt  = (float*)d_ws;
    unsigned short* Xbf = (unsigned short*)((char*)d_ws + WT_BYTES);
    unsigned short* Pbf = (unsigned short*)((char*)d_ws + WT_BYTES + BF_BYTES);

    // C scratch: reuse the trace region of d_out (134 MB >= 52 MB needed);
    // the trace kernel runs last and overwrites it.
    double* C = (double*)trace;

    const int nconv = ws_ok ? 512 : 0;

    transposeW<<<256, 256, 0, stream>>>(W, Wt);
    syn_plus<<<T_STEPS * B_N + nconv, 256, 0, stream>>>(x, Wt, C, Xbf, nconv);
    lif_pointwise<<<B_N * OUT_F / 256, 256, 0, stream>>>(C, S_out, Uh,
                                                         ws_ok ? (unsigned int*)Pbf : nullptr);
    if (ws_ok)
        trace_mfma2<<<32 * B_N, 256, 0, stream>>>(Pbf, Xbf, trace);
    else
        trace_mfma<<<16 * B_N, 256, 0, stream>>>(x, Uh, trace);
}